// Round 1
// baseline (302.224 us; speedup 1.0000x reference)
//
#include <hip/hip_runtime.h>
#include <math.h>

#define BB 64
#define SS 512
#define FF 128
#define UU 512
#define NBB 8
#define SIGDIM (FF + FF*FF)   // 16512
#define K3 16512              // sig GEMM K
#define KK 1152               // KAN GEMM K: 1024 spline + 128 base

typedef __attribute__((ext_vector_type(8))) __bf16 bf16x8;
typedef __attribute__((ext_vector_type(8))) unsigned short u16x8;
typedef __attribute__((ext_vector_type(4))) float f32x4;

__device__ __forceinline__ unsigned short f2bf(float x) {
    unsigned int u = __float_as_uint(x);
    unsigned int r = u + 0x7FFFu + ((u >> 16) & 1u);   // RNE
    return (unsigned short)(r >> 16);
}

__device__ __forceinline__ float sigmoidf(float x) { return 1.0f / (1.0f + expf(-x)); }

// ---------------------------------------------------------------------------
// K1: Wt bf16 [512 u][1152 k] = [splw(u,:,:) flat | base_w^T]
//     + copy h_prev into right half of comb_b
// ---------------------------------------------------------------------------
__global__ void k_wprep(const float* __restrict__ splw, const float* __restrict__ basew,
                        const float* __restrict__ h_prev,
                        unsigned short* __restrict__ Wt, unsigned short* __restrict__ comb_b) {
    int idx = blockIdx.x * 256 + threadIdx.x;
    if (idx >= UU * KK) return;
    int u = idx / KK, c = idx % KK;
    float v = (c < 1024) ? splw[(size_t)u * 1024 + c] : basew[(size_t)(c - 1024) * UU + u];
    Wt[idx] = f2bf(v);
    if (idx < BB * UU) {
        int b = idx >> 9, uu = idx & 511;
        comb_b[(size_t)b * 1024 + 512 + uu] = f2bf(h_prev[idx]);
    }
}

// ---------------------------------------------------------------------------
// K2: transpose small weights -> bf16 B^T.
// ---------------------------------------------------------------------------
__global__ __launch_bounds__(256) void k_wt3(const float* __restrict__ w2, const float* __restrict__ w3,
                                             const float* __restrict__ w4, const float* __restrict__ wf,
                                             const float* __restrict__ wi, const float* __restrict__ wc,
                                             const float* __restrict__ wo,
                                             unsigned short* __restrict__ W2t,
                                             unsigned short* __restrict__ W3t,
                                             unsigned short* __restrict__ W4t,
                                             unsigned short* __restrict__ Wgt) {
    int kt = blockIdx.x, ut = blockIdx.y, z = blockIdx.z;
    int Kdim = (z < 3) ? 512 : 1024;
    if (kt * 64 >= Kdim) return;
    const float* src;
    unsigned short* dst;
    switch (z) {
        case 0: src = w2; dst = W2t; break;
        case 1: src = w3; dst = W3t; break;
        case 2: src = w4; dst = W4t; break;
        case 3: src = wf; dst = Wgt; break;
        case 4: src = wi; dst = Wgt + (size_t)512 * 1024; break;
        case 5: src = wc; dst = Wgt + (size_t)1024 * 1024; break;
        default: src = wo; dst = Wgt + (size_t)1536 * 1024; break;
    }
    __shared__ float tile[64][65];
    int tid = threadIdx.x;
    int k0 = kt * 64, u0 = ut * 64;
#pragma unroll
    for (int p = 0; p < 16; ++p) {
        int e = p * 256 + tid;
        int kk = e >> 6, uu = e & 63;
        tile[kk][uu] = src[(size_t)(k0 + kk) * UU + u0 + uu];
    }
    __syncthreads();
#pragma unroll
    for (int p = 0; p < 16; ++p) {
        int e = p * 256 + tid;
        int uu = e >> 6, kk = e & 63;
        dst[(size_t)(u0 + uu) * Kdim + k0 + kk] = f2bf(tile[kk][uu]);
    }
}

// ---------------------------------------------------------------------------
// K3: transpose w1 / skip_w (16512 x 512 fp32) -> bf16 [512][16512]
// ---------------------------------------------------------------------------
__global__ __launch_bounds__(256) void k_wt2(const float* __restrict__ w1,
                                             const float* __restrict__ gsw,
                                             unsigned short* __restrict__ W1t,
                                             unsigned short* __restrict__ Wst) {
    int kt = blockIdx.x, ut = blockIdx.y, mat = blockIdx.z;
    const float* src = mat ? gsw : w1;
    unsigned short* dst = mat ? Wst : W1t;
    __shared__ float tile[64][65];
    int tid = threadIdx.x;
    int k0 = kt * 64, u0 = ut * 64;
#pragma unroll
    for (int p = 0; p < 16; ++p) {
        int e = p * 256 + tid;
        int kk = e >> 6, uu = e & 63;
        tile[kk][uu] = src[(size_t)(k0 + kk) * UU + u0 + uu];
    }
    __syncthreads();
#pragma unroll
    for (int p = 0; p < 16; ++p) {
        int e = p * 256 + tid;
        int uu = e >> 6, kk = e & 63;
        dst[(size_t)(u0 + uu) * K3 + k0 + kk] = f2bf(tile[kk][uu]);
    }
}

// ---------------------------------------------------------------------------
// K4a: a/d/w prep.
// a_t = 0.5(w_t + w_{t+1}) - w_0, d_t = w_{t+1} - w_t  (fp32), transposed to
// bf16 aT/dT [b][f][512] (t=511 zero).  Additionally emits the plain weighted
// input wT[b][f][t] = tk[t]*inp[b,t,f] (bf16, transposed) for k_kan_red.
// grid (8 ttile, 2 ftile, 64 b) x 256.
// ---------------------------------------------------------------------------
__global__ __launch_bounds__(256) void k_adprep(const float* __restrict__ inp,
                                                const float* __restrict__ tk,
                                                unsigned short* __restrict__ aT,
                                                unsigned short* __restrict__ dT,
                                                unsigned short* __restrict__ wT) {
    int tt0 = blockIdx.x * 64, f0 = blockIdx.y * 64, b = blockIdx.z;
    __shared__ float aS[64][65], dS[64][65], wS[64][65];
    __shared__ float tkS[65];
    int tid = threadIdx.x;
    if (tid < 65) { int t = tt0 + tid; tkS[tid] = (t < SS) ? tk[t] : 0.f; }
    __syncthreads();
    const float* ib = inp + (size_t)b * SS * FF;
    float tk0 = tk[0];
    for (int e = tid; e < 64 * 64; e += 256) {
        int tt = e >> 6, ff = e & 63;
        int t = tt0 + tt;
        int f = f0 + ff;
        float wv = tkS[tt] * ib[(size_t)t * FF + f];
        float av = 0.f, dv = 0.f;
        if (t < SS - 1) {
            float wn = tkS[tt + 1] * ib[(size_t)(t + 1) * FF + f];
            float w0 = tk0 * ib[f];
            av = 0.5f * (wv + wn) - w0;
            dv = wn - wv;
        }
        aS[tt][ff] = av; dS[tt][ff] = dv; wS[tt][ff] = wv;
    }
    __syncthreads();
    for (int e = tid; e < 64 * 64; e += 256) {
        int ff = e >> 6, tt = e & 63;
        size_t o = ((size_t)b * FF + f0 + ff) * SS + tt0 + tt;
        aT[o] = f2bf(aS[tt][ff]);
        dT[o] = f2bf(dS[tt][ff]);
        wT[o] = f2bf(wS[tt][ff]);
    }
}

// ---------------------------------------------------------------------------
// K4b: signature MFMA GEMM: s2part[kc][b] = aT[b](128x128 K-slice) . dT[b]^T
// grid (4 kc, 64 b) x 256 (4 waves, 64x64 quadrant each).  Direct global
// fragment loads, no LDS, no barriers.
// ---------------------------------------------------------------------------
__global__ __launch_bounds__(256) void k_sig_mfma(const unsigned short* __restrict__ aT,
                                                  const unsigned short* __restrict__ dT,
                                                  float* __restrict__ s2part) {
    int kc = blockIdx.x, b = blockIdx.y;
    int tid = threadIdx.x, lane = tid & 63;
    int wv = __builtin_amdgcn_readfirstlane(tid >> 6);
    int wrow = (wv & 1) * 64, wcol = (wv >> 1) * 64;
    int k0 = kc * 128;
    const unsigned short* pa = aT + ((size_t)b * FF + wrow + (lane & 15)) * SS + k0 + (lane >> 4) * 8;
    const unsigned short* pd = dT + ((size_t)b * FF + wcol + (lane & 15)) * SS + k0 + (lane >> 4) * 8;
    f32x4 acc[4][4];
#pragma unroll
    for (int i = 0; i < 4; ++i)
#pragma unroll
        for (int j = 0; j < 4; ++j) acc[i][j] = (f32x4)(0.f);
#pragma unroll
    for (int t = 0; t < 4; ++t) {
        bf16x8 af[4], df[4];
#pragma unroll
        for (int rt = 0; rt < 4; ++rt) af[rt] = *(const bf16x8*)(pa + (size_t)rt * 16 * SS + t * 32);
#pragma unroll
        for (int ct = 0; ct < 4; ++ct) df[ct] = *(const bf16x8*)(pd + (size_t)ct * 16 * SS + t * 32);
#pragma unroll
        for (int rt = 0; rt < 4; ++rt)
#pragma unroll
            for (int ct = 0; ct < 4; ++ct)
                acc[rt][ct] = __builtin_amdgcn_mfma_f32_16x16x32_bf16(af[rt], df[ct], acc[rt][ct], 0, 0, 0);
    }
    float* outp = s2part + ((size_t)kc * BB + b) * (FF * FF);
    int quad = lane >> 4, col = lane & 15;
#pragma unroll
    for (int rt = 0; rt < 4; ++rt)
#pragma unroll
        for (int ct = 0; ct < 4; ++ct)
#pragma unroll
            for (int reg = 0; reg < 4; ++reg)
                outp[(wrow + rt * 16 + quad * 4 + reg) * FF + wcol + ct * 16 + col] = acc[rt][ct][reg];
}

// ---------------------------------------------------------------------------
// K5: assemble sig directly as bf16
// ---------------------------------------------------------------------------
__global__ void k_sig_reduce(const float* __restrict__ inp, const float* __restrict__ tk,
                             const float* __restrict__ s2part, unsigned short* __restrict__ sigb) {
    int idx = blockIdx.x * 256 + threadIdx.x;
    if (idx >= BB * SIGDIM) return;
    int b = idx / SIGDIM, r = idx % SIGDIM;
    float v;
    if (r < FF) {
        v = tk[SS - 1] * inp[((size_t)b * SS + SS - 1) * FF + r] - tk[0] * inp[(size_t)b * SS * FF + r];
    } else {
        int ij = r - FF;
        v = 0.f;
#pragma unroll
        for (int c = 0; c < 4; ++c) v += s2part[((size_t)c * BB + b) * (FF * FF) + ij];
    }
    sigb[idx] = f2bf(v);
}

// ---------------------------------------------------------------------------
// K6: direct single-wave MFMA: {h1,skip} = sigb[64][16512] @ {W1t,Wst}^T
// ---------------------------------------------------------------------------
__global__ __launch_bounds__(64) void k_sig_direct(const unsigned short* __restrict__ sigb,
                                                   const unsigned short* __restrict__ W1t,
                                                   const unsigned short* __restrict__ Wst,
                                                   const float* __restrict__ b1,
                                                   unsigned short* __restrict__ h1b,
                                                   float* __restrict__ skippre) {
    int lane = threadIdx.x;
    int mt = blockIdx.x, nt = blockIdx.y, mat = blockIdx.z;
    const unsigned short* Bp = mat ? Wst : W1t;
    const unsigned short* pa = sigb + (size_t)(mt * 16 + (lane & 15)) * K3 + (lane >> 4) * 8;
    const unsigned short* pb = Bp + (size_t)(nt * 16 + (lane & 15)) * K3 + (lane >> 4) * 8;
    f32x4 acc0 = (f32x4)(0.f), acc1 = (f32x4)(0.f);
#pragma unroll 8
    for (int t = 0; t < K3 / 32; t += 2) {
        bf16x8 a0 = *(const bf16x8*)(pa + t * 32);
        bf16x8 b0 = *(const bf16x8*)(pb + t * 32);
        bf16x8 a1 = *(const bf16x8*)(pa + t * 32 + 32);
        bf16x8 b1v = *(const bf16x8*)(pb + t * 32 + 32);
        acc0 = __builtin_amdgcn_mfma_f32_16x16x32_bf16(a0, b0, acc0, 0, 0, 0);
        acc1 = __builtin_amdgcn_mfma_f32_16x16x32_bf16(a1, b1v, acc1, 0, 0, 0);
    }
    int col = lane & 15, quad = lane >> 4;
    int j = nt * 16 + col;
    if (mat == 0) {
        float bb = b1[j];
#pragma unroll
        for (int reg = 0; reg < 4; ++reg) {
            int row = mt * 16 + quad * 4 + reg;
            float v = acc0[reg] + acc1[reg] + bb;
            h1b[(size_t)row * UU + j] = f2bf(v > 0.f ? v : expf(v) - 1.0f);
        }
    } else {
#pragma unroll
        for (int reg = 0; reg < 4; ++reg) {
            int row = mt * 16 + quad * 4 + reg;
            skippre[(size_t)row * UU + j] = acc0[reg] + acc1[reg];
        }
    }
}

// ---------------------------------------------------------------------------
// K7: direct h2 = h1b @ W2t^T + b2 -> bf16
// ---------------------------------------------------------------------------
__global__ __launch_bounds__(64) void k_h2_direct(const unsigned short* __restrict__ h1b,
                                                  const unsigned short* __restrict__ W2t,
                                                  const float* __restrict__ b2,
                                                  unsigned short* __restrict__ h2b) {
    int lane = threadIdx.x;
    int mt = blockIdx.x, nt = blockIdx.y;
    const unsigned short* pa = h1b + (size_t)(mt * 16 + (lane & 15)) * 512 + (lane >> 4) * 8;
    const unsigned short* pb = W2t + (size_t)(nt * 16 + (lane & 15)) * 512 + (lane >> 4) * 8;
    f32x4 acc0 = (f32x4)(0.f), acc1 = (f32x4)(0.f);
#pragma unroll
    for (int t = 0; t < 16; t += 2) {
        bf16x8 a0 = *(const bf16x8*)(pa + t * 32);
        bf16x8 b0 = *(const bf16x8*)(pb + t * 32);
        bf16x8 a1 = *(const bf16x8*)(pa + t * 32 + 32);
        bf16x8 b1v = *(const bf16x8*)(pb + t * 32 + 32);
        acc0 = __builtin_amdgcn_mfma_f32_16x16x32_bf16(a0, b0, acc0, 0, 0, 0);
        acc1 = __builtin_amdgcn_mfma_f32_16x16x32_bf16(a1, b1v, acc1, 0, 0, 0);
    }
    int col = lane & 15, quad = lane >> 4;
    int j = nt * 16 + col;
    float bb = b2[j];
#pragma unroll
    for (int reg = 0; reg < 4; ++reg) {
        int row = mt * 16 + quad * 4 + reg;
        h2b[(size_t)row * UU + j] = f2bf(acc0[reg] + acc1[reg] + bb);
    }
}

// ---------------------------------------------------------------------------
// K8: direct GLU
// ---------------------------------------------------------------------------
__global__ __launch_bounds__(64) void k_glu_direct(const unsigned short* __restrict__ h2b,
                                                   const unsigned short* __restrict__ W3t,
                                                   const unsigned short* __restrict__ W4t,
                                                   const float* __restrict__ b3,
                                                   const float* __restrict__ b4,
                                                   const float* __restrict__ skippre,
                                                   const float* __restrict__ skb,
                                                   float* __restrict__ yv) {
    int lane = threadIdx.x;
    int mt = blockIdx.x, nt = blockIdx.y;
    const unsigned short* pa = h2b + (size_t)(mt * 16 + (lane & 15)) * 512 + (lane >> 4) * 8;
    const unsigned short* pb3 = W3t + (size_t)(nt * 16 + (lane & 15)) * 512 + (lane >> 4) * 8;
    const unsigned short* pb4 = W4t + (size_t)(nt * 16 + (lane & 15)) * 512 + (lane >> 4) * 8;
    f32x4 acc3 = (f32x4)(0.f), acc4 = (f32x4)(0.f);
#pragma unroll
    for (int t = 0; t < 16; ++t) {
        bf16x8 a = *(const bf16x8*)(pa + t * 32);
        bf16x8 b3f = *(const bf16x8*)(pb3 + t * 32);
        bf16x8 b4f = *(const bf16x8*)(pb4 + t * 32);
        acc3 = __builtin_amdgcn_mfma_f32_16x16x32_bf16(a, b3f, acc3, 0, 0, 0);
        acc4 = __builtin_amdgcn_mfma_f32_16x16x32_bf16(a, b4f, acc4, 0, 0, 0);
    }
    int col = lane & 15, quad = lane >> 4;
    int j = nt * 16 + col;
    float bb3 = b3[j], bb4 = b4[j], sb = skb[j];
#pragma unroll
    for (int reg = 0; reg < 4; ++reg) {
        int row = mt * 16 + quad * 4 + reg;
        float g = sigmoidf(acc3[reg] + bb3);
        yv[(size_t)row * UU + j] = skippre[(size_t)row * UU + j] + sb + g * (acc4[reg] + bb4);
    }
}

// ---------------------------------------------------------------------------
// K9: layernorm + softmax -> attn
// ---------------------------------------------------------------------------
__device__ __forceinline__ float block_sum(float v, float* red) {
    int tid = threadIdx.x;
#pragma unroll
    for (int off = 32; off > 0; off >>= 1) v += __shfl_down(v, off);
    __syncthreads();
    if ((tid & 63) == 0) red[tid >> 6] = v;
    __syncthreads();
    float r = red[0];
#pragma unroll
    for (int i = 1; i < 8; ++i) r += red[i];
    return r;
}
__device__ __forceinline__ float block_max(float v, float* red) {
    int tid = threadIdx.x;
#pragma unroll
    for (int off = 32; off > 0; off >>= 1) v = fmaxf(v, __shfl_down(v, off));
    __syncthreads();
    if ((tid & 63) == 0) red[tid >> 6] = v;
    __syncthreads();
    float r = red[0];
#pragma unroll
    for (int i = 1; i < 8; ++i) r = fmaxf(r, red[i]);
    return r;
}

__global__ void k_lnsm(const float* __restrict__ yv, const float* __restrict__ gamma,
                       const float* __restrict__ beta, float* __restrict__ attn) {
    int b = blockIdx.x, u = threadIdx.x;
    __shared__ float red[8];
    float v = yv[(size_t)b * UU + u];
    float mu = block_sum(v, red) * (1.0f / UU);
    float d = v - mu;
    float var = block_sum(d * d, red) * (1.0f / UU);
    float z = d * rsqrtf(var + 1e-3f) * gamma[u] + beta[u];
    float m = block_max(z, red);
    float e = expf(z - m);
    float Z = block_sum(e, red);
    attn[(size_t)b * UU + u] = e / Z;
}

// ---------------------------------------------------------------------------
// K10: attn-weighted KAN-feature reduction, lane-parallel over s.
// One wave per (b, f): each lane owns 8 consecutive timesteps (bf16x8 load of
// the pre-transposed weighted input wT[b][f][:]), evaluates the closed-form
// cubic B-spline basis + silu, weights by attn[b][s], butterfly-reduces the
// 9 accumulators across the wave, and writes Aredb directly (no Apart pass).
// grid (64 b, 32 fg) x 256 (4 waves/block, one f per wave).
// ---------------------------------------------------------------------------
__global__ __launch_bounds__(256) void k_kan_red(const unsigned short* __restrict__ wT,
                                                 const float* __restrict__ attn,
                                                 unsigned short* __restrict__ Aredb) {
    int b = blockIdx.x;
    int lane = threadIdx.x & 63;
    int f = blockIdx.y * 4 + (threadIdx.x >> 6);

    const u16x8 wv = *(const u16x8*)(wT + ((size_t)b * FF + f) * SS + lane * 8);
    const float* ap = attn + (size_t)b * UU + lane * 8;
    float4 a0 = *(const float4*)ap;
    float4 a1 = *(const float4*)(ap + 4);

    float acc[9] = {};
#pragma unroll
    for (int s = 0; s < 8; ++s) {
        float w = __uint_as_float((unsigned int)wv[s] << 16);
        float a = (s < 4) ? ((s == 0) ? a0.x : (s == 1) ? a0.y : (s == 2) ? a0.z : a0.w)
                          : ((s == 4) ? a1.x : (s == 5) ? a1.y : (s == 6) ? a1.z : a1.w);
        float t = (w + 2.2f) * 2.5f;
        float cf = floorf(fminf(fmaxf(t, -2.f), 13.f));
        int c = (int)cf;
        float u = t - cf;
        float u2 = u * u, u3 = u2 * u;
        float p0 = u3 * (1.f / 6.f);
        float p1 = (-3.f * u3 + 3.f * u2 + 3.f * u + 1.f) * (1.f / 6.f);
        float p2 = (3.f * u3 - 6.f * u2 + 4.f) * (1.f / 6.f);
        float onemu = 1.f - u;
        float p3 = onemu * onemu * onemu * (1.f / 6.f);
#pragma unroll
        for (int k2 = 0; k2 < 8; ++k2) {
            int d = c - k2;
            float v = (d == 0) ? p0 : (d == 1) ? p1 : (d == 2) ? p2 : (d == 3) ? p3 : 0.f;
            acc[k2] += a * v;
        }
        acc[8] += a * (w * sigmoidf(w));
    }

    // wave butterfly reduce all 9 accumulators
#pragma unroll
    for (int off = 1; off < 64; off <<= 1) {
#pragma unroll
        for (int k = 0; k < 9; ++k) acc[k] += __shfl_xor(acc[k], off);
    }

    if (lane == 0) {
        const float sc = 1.0f / SS;
        u16x8 ov;
#pragma unroll
        for (int k = 0; k < 8; ++k) ov[k] = f2bf(acc[k] * sc);
        *(u16x8*)(Aredb + (size_t)b * KK + f * 8) = ov;
        Aredb[(size_t)b * KK + 1024 + f] = f2bf(acc[8] * sc);
    }
}

// ---------------------------------------------------------------------------
// K12: direct current = Aredb @ Wt^T -> bf16 into comb_b left half
// ---------------------------------------------------------------------------
__global__ __launch_bounds__(64) void k_cur_direct(const unsigned short* __restrict__ Aredb,
                                                   const unsigned short* __restrict__ Wt,
                                                   unsigned short* __restrict__ comb_b) {
    int lane = threadIdx.x;
    int mt = blockIdx.x, nt = blockIdx.y;
    const unsigned short* pa = Aredb + (size_t)(mt * 16 + (lane & 15)) * KK + (lane >> 4) * 8;
    const unsigned short* pb = Wt + (size_t)(nt * 16 + (lane & 15)) * KK + (lane >> 4) * 8;
    f32x4 acc0 = (f32x4)(0.f), acc1 = (f32x4)(0.f);
#pragma unroll 6
    for (int t = 0; t < KK / 32; t += 2) {
        bf16x8 a0 = *(const bf16x8*)(pa + t * 32);
        bf16x8 b0 = *(const bf16x8*)(pb + t * 32);
        bf16x8 a1 = *(const bf16x8*)(pa + t * 32 + 32);
        bf16x8 b1v = *(const bf16x8*)(pb + t * 32 + 32);
        acc0 = __builtin_amdgcn_mfma_f32_16x16x32_bf16(a0, b0, acc0, 0, 0, 0);
        acc1 = __builtin_amdgcn_mfma_f32_16x16x32_bf16(a1, b1v, acc1, 0, 0, 0);
    }
    int col = lane & 15, quad = lane >> 4;
    int j = nt * 16 + col;
#pragma unroll
    for (int reg = 0; reg < 4; ++reg) {
        int row = mt * 16 + quad * 4 + reg;
        comb_b[(size_t)row * 1024 + j] = f2bf(acc0[reg] + acc1[reg]);
    }
}

// ---------------------------------------------------------------------------
// K13: direct gates = comb_b @ Wgt^T
// ---------------------------------------------------------------------------
__global__ __launch_bounds__(64) void k_gates_direct(const unsigned short* __restrict__ comb_b,
                                                     const unsigned short* __restrict__ Wgt,
                                                     float* __restrict__ gates) {
    int lane = threadIdx.x;
    int mt = blockIdx.x, nt = blockIdx.y;
    const unsigned short* pa = comb_b + (size_t)(mt * 16 + (lane & 15)) * 1024 + (lane >> 4) * 8;
    const unsigned short* pb = Wgt + (size_t)(nt * 16 + (lane & 15)) * 1024 + (lane >> 4) * 8;
    f32x4 acc0 = (f32x4)(0.f), acc1 = (f32x4)(0.f);
#pragma unroll 8
    for (int t = 0; t < 32; t += 2) {
        bf16x8 a0 = *(const bf16x8*)(pa + t * 32);
        bf16x8 b0 = *(const bf16x8*)(pb + t * 32);
        bf16x8 a1 = *(const bf16x8*)(pa + t * 32 + 32);
        bf16x8 b1v = *(const bf16x8*)(pb + t * 32 + 32);
        acc0 = __builtin_amdgcn_mfma_f32_16x16x32_bf16(a0, b0, acc0, 0, 0, 0);
        acc1 = __builtin_amdgcn_mfma_f32_16x16x32_bf16(a1, b1v, acc1, 0, 0, 0);
    }
    int col = lane & 15, quad = lane >> 4;
    int j = nt * 16 + col;
#pragma unroll
    for (int reg = 0; reg < 4; ++reg) {
        int row = mt * 16 + quad * 4 + reg;
        gates[(size_t)row * 2048 + j] = acc0[reg] + acc1[reg];
    }
}

// ---------------------------------------------------------------------------
// K14: elementwise cell update
// ---------------------------------------------------------------------------
__global__ void k_cell(const float* __restrict__ gates,
                       const float* __restrict__ bf_, const float* __restrict__ bi_,
                       const float* __restrict__ bc_, const float* __restrict__ bo_,
                       const float* __restrict__ c_prev, float* __restrict__ out) {
    int idx = blockIdx.x * 256 + threadIdx.x;
    if (idx >= BB * UU) return;
    int b = idx >> 9, u = idx & 511;
    const float* g = gates + (size_t)b * 2048;
    float f = sigmoidf(g[u] + bf_[u]);
    float ii = sigmoidf(g[512 + u] + bi_[u]);
    float cd = tanhf(g[1024 + u] + bc_[u]);
    float o = sigmoidf(g[1536 + u] + bo_[u]);
    float cn = f * c_prev[idx] + ii * cd;
    out[idx] = o * tanhf(cn);
    out[(size_t)BB * UU + idx] = cn;
}

// ---------------------------------------------------------------------------
extern "C" void kernel_launch(void* const* d_in, const int* in_sizes, int n_in,
                              void* d_out, int out_size, void* d_ws, size_t ws_size,
                              hipStream_t stream) {
    const float* inp   = (const float*)d_in[0];
    const float* hprev = (const float*)d_in[1];
    const float* cprev = (const float*)d_in[2];
    const float* tk    = (const float*)d_in[3];
    const float* basew = (const float*)d_in[4];
    const float* splw  = (const float*)d_in[5];
    const float* gw1   = (const float*)d_in[6];
    const float* gb1   = (const float*)d_in[7];
    const float* gw2   = (const float*)d_in[8];
    const float* gb2   = (const float*)d_in[9];
    const float* gw3   = (const float*)d_in[10];
    const float* gb3   = (const float*)d_in[11];
    const float* gw4   = (const float*)d_in[12];
    const float* gb4   = (const float*)d_in[13];
    const float* gsw   = (const float*)d_in[14];
    const float* gsb   = (const float*)d_in[15];
    const float* lng   = (const float*)d_in[16];
    const float* lnb   = (const float*)d_in[17];
    const float* wf    = (const float*)d_in[18];
    const float* bf_   = (const float*)d_in[19];
    const float* wi    = (const float*)d_in[20];
    const float* bi_   = (const float*)d_in[21];
    const float* wc    = (const float*)d_in[22];
    const float* bc_   = (const float*)d_in[23];
    const float* wo    = (const float*)d_in[24];
    const float* bo_   = (const float*)d_in[25];
    float* out = (float*)d_out;

    float* ws = (float*)d_ws;
    size_t o = 0;
    unsigned short* W1t = (unsigned short*)(ws + o); o += (size_t)UU * K3 / 2;   // 16.9 MB
    unsigned short* Wst = (unsigned short*)(ws + o); o += (size_t)UU * K3 / 2;   // 16.9 MB
    unsigned short* Wt  = (unsigned short*)(ws + o); o += (size_t)UU * KK / 2;
    float* s2part   = ws + o; o += (size_t)4 * BB * FF * FF;                     // 16.78 MB
    unsigned short* aT = (unsigned short*)(ws + o); o += (size_t)BB * FF * SS / 2;  // 8.4 MB
    unsigned short* dT = (unsigned short*)(ws + o); o += (size_t)BB * FF * SS / 2;  // 8.4 MB
    unsigned short* wT = (unsigned short*)(ws + o); o += (size_t)BB * FF * SS / 2;  // 8.4 MB
    unsigned short* sigb = (unsigned short*)(ws + o); o += (size_t)BB * K3 / 2;
    float* skippre  = ws + o; o += (size_t)BB * UU;
    unsigned short* h1b = (unsigned short*)(ws + o); o += (size_t)BB * UU / 2;
    unsigned short* h2b = (unsigned short*)(ws + o); o += (size_t)BB * UU / 2;
    float* yv       = ws + o; o += (size_t)BB * UU;
    float* attn     = ws + o; o += (size_t)BB * UU;
    unsigned short* Aredb = (unsigned short*)(ws + o); o += (size_t)BB * KK / 2;
    unsigned short* W2t = (unsigned short*)(ws + o); o += (size_t)512 * 512 / 2;
    unsigned short* W3t = (unsigned short*)(ws + o); o += (size_t)512 * 512 / 2;
    unsigned short* W4t = (unsigned short*)(ws + o); o += (size_t)512 * 512 / 2;
    unsigned short* Wgt = (unsigned short*)(ws + o); o += (size_t)2048 * 1024 / 2;
    unsigned short* comb_b = (unsigned short*)(ws + o); o += (size_t)BB * 1024 / 2;
    float* gates    = ws + o; o += (size_t)BB * 2048;
    (void)ws_size; (void)in_sizes; (void)n_in; (void)out_size;

    k_wprep<<<(UU * KK + 255) / 256, 256, 0, stream>>>(splw, basew, hprev, Wt, comb_b);
    k_wt3<<<dim3(16, 8, 7), 256, 0, stream>>>(gw2, gw3, gw4, wf, wi, wc, wo, W2t, W3t, W4t, Wgt);
    k_wt2<<<dim3(K3 / 64, UU / 64, 2), 256, 0, stream>>>(gw1, gsw, W1t, Wst);
    k_adprep<<<dim3(8, 2, BB), 256, 0, stream>>>(inp, tk, aT, dT, wT);
    k_sig_mfma<<<dim3(4, BB), 256, 0, stream>>>(aT, dT, s2part);
    k_sig_reduce<<<(BB * SIGDIM + 255) / 256, 256, 0, stream>>>(inp, tk, s2part, sigb);
    k_sig_direct<<<dim3(4, 32, 2), 64, 0, stream>>>(sigb, W1t, Wst, gb1, h1b, skippre);
    k_h2_direct<<<dim3(4, 32), 64, 0, stream>>>(h1b, W2t, gb2, h2b);
    k_glu_direct<<<dim3(4, 32), 64, 0, stream>>>(h2b, W3t, W4t, gb3, gb4, skippre, gsb, yv);
    k_lnsm<<<BB, UU, 0, stream>>>(yv, lng, lnb, attn);
    k_kan_red<<<dim3(BB, FF / 4), 256, 0, stream>>>(wT, attn, Aredb);
    k_cur_direct<<<dim3(4, 32), 64, 0, stream>>>(Aredb, Wt, comb_b);
    k_gates_direct<<<dim3(4, 128), 64, 0, stream>>>(comb_b, Wgt, gates);
    k_cell<<<(BB * UU + 255) / 256, 256, 0, stream>>>(gates, bf_, bi_, bc_, bo_, cprev, out);
}

// Round 2
// 273.863 us; speedup vs baseline: 1.1036x; 1.1036x over previous
//
#include <hip/hip_runtime.h>
#include <math.h>

#define BB 64
#define SS 512
#define FF 128
#define UU 512
#define NBB 8
#define SIGDIM (FF + FF*FF)   // 16512
#define K3 16512              // sig GEMM K
#define KK 1152               // KAN GEMM K: 1024 spline + 128 base

typedef __attribute__((ext_vector_type(8))) __bf16 bf16x8;
typedef __attribute__((ext_vector_type(8))) unsigned short u16x8;
typedef __attribute__((ext_vector_type(4))) float f32x4;

__device__ __forceinline__ unsigned short f2bf(float x) {
    unsigned int u = __float_as_uint(x);
    unsigned int r = u + 0x7FFFu + ((u >> 16) & 1u);   // RNE
    return (unsigned short)(r >> 16);
}

__device__ __forceinline__ float sigmoidf(float x) { return 1.0f / (1.0f + expf(-x)); }

// ---------------------------------------------------------------------------
// K1: Wt bf16 [512 u][1152 k] = [splw(u,:,:) flat | base_w^T]
//     + copy h_prev into right half of comb_b
// ---------------------------------------------------------------------------
__global__ void k_wprep(const float* __restrict__ splw, const float* __restrict__ basew,
                        const float* __restrict__ h_prev,
                        unsigned short* __restrict__ Wt, unsigned short* __restrict__ comb_b) {
    int idx = blockIdx.x * 256 + threadIdx.x;
    if (idx >= UU * KK) return;
    int u = idx / KK, c = idx % KK;
    float v = (c < 1024) ? splw[(size_t)u * 1024 + c] : basew[(size_t)(c - 1024) * UU + u];
    Wt[idx] = f2bf(v);
    if (idx < BB * UU) {
        int b = idx >> 9, uu = idx & 511;
        comb_b[(size_t)b * 1024 + 512 + uu] = f2bf(h_prev[idx]);
    }
}

// ---------------------------------------------------------------------------
// K2: transpose small weights -> bf16 B^T.  float4 loads into fp32 LDS tile,
// packed u16x8 transposed stores (16 B/lane).
// ---------------------------------------------------------------------------
__global__ __launch_bounds__(256) void k_wt3(const float* __restrict__ w2, const float* __restrict__ w3,
                                             const float* __restrict__ w4, const float* __restrict__ wf,
                                             const float* __restrict__ wi, const float* __restrict__ wc,
                                             const float* __restrict__ wo,
                                             unsigned short* __restrict__ W2t,
                                             unsigned short* __restrict__ W3t,
                                             unsigned short* __restrict__ W4t,
                                             unsigned short* __restrict__ Wgt) {
    int kt = blockIdx.x, ut = blockIdx.y, z = blockIdx.z;
    int Kdim = (z < 3) ? 512 : 1024;
    if (kt * 64 >= Kdim) return;
    const float* src;
    unsigned short* dst;
    switch (z) {
        case 0: src = w2; dst = W2t; break;
        case 1: src = w3; dst = W3t; break;
        case 2: src = w4; dst = W4t; break;
        case 3: src = wf; dst = Wgt; break;
        case 4: src = wi; dst = Wgt + (size_t)512 * 1024; break;
        case 5: src = wc; dst = Wgt + (size_t)1024 * 1024; break;
        default: src = wo; dst = Wgt + (size_t)1536 * 1024; break;
    }
    __shared__ float tile[64][67];
    int tid = threadIdx.x;
    int k0 = kt * 64, u0 = ut * 64;
#pragma unroll
    for (int p = 0; p < 4; ++p) {
        int e = p * 256 + tid;
        int kk = e >> 4, c4 = (e & 15) * 4;
        const float4 v = *(const float4*)(src + (size_t)(k0 + kk) * UU + u0 + c4);
        tile[kk][c4 + 0] = v.x;
        tile[kk][c4 + 1] = v.y;
        tile[kk][c4 + 2] = v.z;
        tile[kk][c4 + 3] = v.w;
    }
    __syncthreads();
    int kk0 = (tid & 7) * 8;
#pragma unroll
    for (int p = 0; p < 2; ++p) {
        int uu = (tid >> 3) + p * 32;
        u16x8 ov;
#pragma unroll
        for (int j = 0; j < 8; ++j) ov[j] = f2bf(tile[kk0 + j][uu]);
        *(u16x8*)(dst + (size_t)(u0 + uu) * Kdim + k0 + kk0) = ov;
    }
}

// ---------------------------------------------------------------------------
// K3: transpose w1 / skip_w (16512 x 512 fp32) -> bf16 [512][16512]
// float4 loads, u16x8 packed transposed stores.
// ---------------------------------------------------------------------------
__global__ __launch_bounds__(256) void k_wt2(const float* __restrict__ w1,
                                             const float* __restrict__ gsw,
                                             unsigned short* __restrict__ W1t,
                                             unsigned short* __restrict__ Wst) {
    int kt = blockIdx.x, ut = blockIdx.y, mat = blockIdx.z;
    const float* src = mat ? gsw : w1;
    unsigned short* dst = mat ? Wst : W1t;
    __shared__ float tile[64][67];
    int tid = threadIdx.x;
    int k0 = kt * 64, u0 = ut * 64;
#pragma unroll
    for (int p = 0; p < 4; ++p) {
        int e = p * 256 + tid;
        int kk = e >> 4, c4 = (e & 15) * 4;
        const float4 v = *(const float4*)(src + (size_t)(k0 + kk) * UU + u0 + c4);
        tile[kk][c4 + 0] = v.x;
        tile[kk][c4 + 1] = v.y;
        tile[kk][c4 + 2] = v.z;
        tile[kk][c4 + 3] = v.w;
    }
    __syncthreads();
    int kk0 = (tid & 7) * 8;
#pragma unroll
    for (int p = 0; p < 2; ++p) {
        int uu = (tid >> 3) + p * 32;
        u16x8 ov;
#pragma unroll
        for (int j = 0; j < 8; ++j) ov[j] = f2bf(tile[kk0 + j][uu]);
        *(u16x8*)(dst + (size_t)(u0 + uu) * K3 + k0 + kk0) = ov;
    }
}

// ---------------------------------------------------------------------------
// K4a: a/d/w prep, single fp32 LDS tile.
// Phase 1: wS[row][ff] = tk[t]*inp[b,t,f] for rows 0..64 (float4 loads, each
// input element read exactly once).  Phase 2: compute a/d/w from wS[tt],
// wS[tt+1], w0S and store packed u16x8 (16 B/lane, full-line writes).
// grid (8 ttile, 2 ftile, 64 b) x 256.  LDS ~17.7 KB -> 8 blocks/CU.
// ---------------------------------------------------------------------------
__global__ __launch_bounds__(256) void k_adprep(const float* __restrict__ inp,
                                                const float* __restrict__ tk,
                                                unsigned short* __restrict__ aT,
                                                unsigned short* __restrict__ dT,
                                                unsigned short* __restrict__ wT) {
    int tt0 = blockIdx.x * 64, f0 = blockIdx.y * 64, b = blockIdx.z;
    __shared__ float wS[65][67];
    __shared__ float w0S[64];
    int tid = threadIdx.x;
    const float* ib = inp + (size_t)b * SS * FF;
    if (tid < 64) w0S[tid] = tk[0] * ib[f0 + tid];
#pragma unroll
    for (int p = 0; p < 5; ++p) {
        int e = p * 256 + tid;
        if (e < 65 * 16) {
            int row = e >> 4, c4 = (e & 15) * 4;
            int t = tt0 + row;
            if (t < SS) {
                float tkt = tk[t];
                const float4 v = *(const float4*)(ib + (size_t)t * FF + f0 + c4);
                wS[row][c4 + 0] = tkt * v.x;
                wS[row][c4 + 1] = tkt * v.y;
                wS[row][c4 + 2] = tkt * v.z;
                wS[row][c4 + 3] = tkt * v.w;
            } else {
                wS[row][c4 + 0] = 0.f;
                wS[row][c4 + 1] = 0.f;
                wS[row][c4 + 2] = 0.f;
                wS[row][c4 + 3] = 0.f;
            }
        }
    }
    __syncthreads();
    int t8 = (tid & 7) * 8;
#pragma unroll
    for (int p = 0; p < 2; ++p) {
        int ff = (tid >> 3) + p * 32;
        float w0 = w0S[ff];
        u16x8 av, dv, wv;
#pragma unroll
        for (int j = 0; j < 8; ++j) {
            int tt = t8 + j;
            float w = wS[tt][ff];
            float wn = wS[tt + 1][ff];
            bool valid = (tt0 + tt) < (SS - 1);
            float a = valid ? 0.5f * (w + wn) - w0 : 0.f;
            float d = valid ? wn - w : 0.f;
            av[j] = f2bf(a);
            dv[j] = f2bf(d);
            wv[j] = f2bf(w);
        }
        size_t o = ((size_t)b * FF + f0 + ff) * SS + tt0 + t8;
        *(u16x8*)(aT + o) = av;
        *(u16x8*)(dT + o) = dv;
        *(u16x8*)(wT + o) = wv;
    }
}

// ---------------------------------------------------------------------------
// K4b: signature MFMA GEMM: s2part[kc][b] = aT[b](128x128 K-slice) . dT[b]^T
// grid (4 kc, 64 b) x 256 (4 waves, 64x64 quadrant each).  Direct global
// fragment loads, no LDS, no barriers.
// ---------------------------------------------------------------------------
__global__ __launch_bounds__(256) void k_sig_mfma(const unsigned short* __restrict__ aT,
                                                  const unsigned short* __restrict__ dT,
                                                  float* __restrict__ s2part) {
    int kc = blockIdx.x, b = blockIdx.y;
    int tid = threadIdx.x, lane = tid & 63;
    int wv = __builtin_amdgcn_readfirstlane(tid >> 6);
    int wrow = (wv & 1) * 64, wcol = (wv >> 1) * 64;
    int k0 = kc * 128;
    const unsigned short* pa = aT + ((size_t)b * FF + wrow + (lane & 15)) * SS + k0 + (lane >> 4) * 8;
    const unsigned short* pd = dT + ((size_t)b * FF + wcol + (lane & 15)) * SS + k0 + (lane >> 4) * 8;
    f32x4 acc[4][4];
#pragma unroll
    for (int i = 0; i < 4; ++i)
#pragma unroll
        for (int j = 0; j < 4; ++j) acc[i][j] = (f32x4)(0.f);
#pragma unroll
    for (int t = 0; t < 4; ++t) {
        bf16x8 af[4], df[4];
#pragma unroll
        for (int rt = 0; rt < 4; ++rt) af[rt] = *(const bf16x8*)(pa + (size_t)rt * 16 * SS + t * 32);
#pragma unroll
        for (int ct = 0; ct < 4; ++ct) df[ct] = *(const bf16x8*)(pd + (size_t)ct * 16 * SS + t * 32);
#pragma unroll
        for (int rt = 0; rt < 4; ++rt)
#pragma unroll
            for (int ct = 0; ct < 4; ++ct)
                acc[rt][ct] = __builtin_amdgcn_mfma_f32_16x16x32_bf16(af[rt], df[ct], acc[rt][ct], 0, 0, 0);
    }
    float* outp = s2part + ((size_t)kc * BB + b) * (FF * FF);
    int quad = lane >> 4, col = lane & 15;
#pragma unroll
    for (int rt = 0; rt < 4; ++rt)
#pragma unroll
        for (int ct = 0; ct < 4; ++ct)
#pragma unroll
            for (int reg = 0; reg < 4; ++reg)
                outp[(wrow + rt * 16 + quad * 4 + reg) * FF + wcol + ct * 16 + col] = acc[rt][ct][reg];
}

// ---------------------------------------------------------------------------
// K5: assemble sig directly as bf16
// ---------------------------------------------------------------------------
__global__ void k_sig_reduce(const float* __restrict__ inp, const float* __restrict__ tk,
                             const float* __restrict__ s2part, unsigned short* __restrict__ sigb) {
    int idx = blockIdx.x * 256 + threadIdx.x;
    if (idx >= BB * SIGDIM) return;
    int b = idx / SIGDIM, r = idx % SIGDIM;
    float v;
    if (r < FF) {
        v = tk[SS - 1] * inp[((size_t)b * SS + SS - 1) * FF + r] - tk[0] * inp[(size_t)b * SS * FF + r];
    } else {
        int ij = r - FF;
        v = 0.f;
#pragma unroll
        for (int c = 0; c < 4; ++c) v += s2part[((size_t)c * BB + b) * (FF * FF) + ij];
    }
    sigb[idx] = f2bf(v);
}

// ---------------------------------------------------------------------------
// K6: direct single-wave MFMA: {h1,skip} = sigb[64][16512] @ {W1t,Wst}^T
// ---------------------------------------------------------------------------
__global__ __launch_bounds__(64) void k_sig_direct(const unsigned short* __restrict__ sigb,
                                                   const unsigned short* __restrict__ W1t,
                                                   const unsigned short* __restrict__ Wst,
                                                   const float* __restrict__ b1,
                                                   unsigned short* __restrict__ h1b,
                                                   float* __restrict__ skippre) {
    int lane = threadIdx.x;
    int mt = blockIdx.x, nt = blockIdx.y, mat = blockIdx.z;
    const unsigned short* Bp = mat ? Wst : W1t;
    const unsigned short* pa = sigb + (size_t)(mt * 16 + (lane & 15)) * K3 + (lane >> 4) * 8;
    const unsigned short* pb = Bp + (size_t)(nt * 16 + (lane & 15)) * K3 + (lane >> 4) * 8;
    f32x4 acc0 = (f32x4)(0.f), acc1 = (f32x4)(0.f);
#pragma unroll 8
    for (int t = 0; t < K3 / 32; t += 2) {
        bf16x8 a0 = *(const bf16x8*)(pa + t * 32);
        bf16x8 b0 = *(const bf16x8*)(pb + t * 32);
        bf16x8 a1 = *(const bf16x8*)(pa + t * 32 + 32);
        bf16x8 b1v = *(const bf16x8*)(pb + t * 32 + 32);
        acc0 = __builtin_amdgcn_mfma_f32_16x16x32_bf16(a0, b0, acc0, 0, 0, 0);
        acc1 = __builtin_amdgcn_mfma_f32_16x16x32_bf16(a1, b1v, acc1, 0, 0, 0);
    }
    int col = lane & 15, quad = lane >> 4;
    int j = nt * 16 + col;
    if (mat == 0) {
        float bb = b1[j];
#pragma unroll
        for (int reg = 0; reg < 4; ++reg) {
            int row = mt * 16 + quad * 4 + reg;
            float v = acc0[reg] + acc1[reg] + bb;
            h1b[(size_t)row * UU + j] = f2bf(v > 0.f ? v : expf(v) - 1.0f);
        }
    } else {
#pragma unroll
        for (int reg = 0; reg < 4; ++reg) {
            int row = mt * 16 + quad * 4 + reg;
            skippre[(size_t)row * UU + j] = acc0[reg] + acc1[reg];
        }
    }
}

// ---------------------------------------------------------------------------
// K7: direct h2 = h1b @ W2t^T + b2 -> bf16
// ---------------------------------------------------------------------------
__global__ __launch_bounds__(64) void k_h2_direct(const unsigned short* __restrict__ h1b,
                                                  const unsigned short* __restrict__ W2t,
                                                  const float* __restrict__ b2,
                                                  unsigned short* __restrict__ h2b) {
    int lane = threadIdx.x;
    int mt = blockIdx.x, nt = blockIdx.y;
    const unsigned short* pa = h1b + (size_t)(mt * 16 + (lane & 15)) * 512 + (lane >> 4) * 8;
    const unsigned short* pb = W2t + (size_t)(nt * 16 + (lane & 15)) * 512 + (lane >> 4) * 8;
    f32x4 acc0 = (f32x4)(0.f), acc1 = (f32x4)(0.f);
#pragma unroll
    for (int t = 0; t < 16; t += 2) {
        bf16x8 a0 = *(const bf16x8*)(pa + t * 32);
        bf16x8 b0 = *(const bf16x8*)(pb + t * 32);
        bf16x8 a1 = *(const bf16x8*)(pa + t * 32 + 32);
        bf16x8 b1v = *(const bf16x8*)(pb + t * 32 + 32);
        acc0 = __builtin_amdgcn_mfma_f32_16x16x32_bf16(a0, b0, acc0, 0, 0, 0);
        acc1 = __builtin_amdgcn_mfma_f32_16x16x32_bf16(a1, b1v, acc1, 0, 0, 0);
    }
    int col = lane & 15, quad = lane >> 4;
    int j = nt * 16 + col;
    float bb = b2[j];
#pragma unroll
    for (int reg = 0; reg < 4; ++reg) {
        int row = mt * 16 + quad * 4 + reg;
        h2b[(size_t)row * UU + j] = f2bf(acc0[reg] + acc1[reg] + bb);
    }
}

// ---------------------------------------------------------------------------
// K8: direct GLU
// ---------------------------------------------------------------------------
__global__ __launch_bounds__(64) void k_glu_direct(const unsigned short* __restrict__ h2b,
                                                   const unsigned short* __restrict__ W3t,
                                                   const unsigned short* __restrict__ W4t,
                                                   const float* __restrict__ b3,
                                                   const float* __restrict__ b4,
                                                   const float* __restrict__ skippre,
                                                   const float* __restrict__ skb,
                                                   float* __restrict__ yv) {
    int lane = threadIdx.x;
    int mt = blockIdx.x, nt = blockIdx.y;
    const unsigned short* pa = h2b + (size_t)(mt * 16 + (lane & 15)) * 512 + (lane >> 4) * 8;
    const unsigned short* pb3 = W3t + (size_t)(nt * 16 + (lane & 15)) * 512 + (lane >> 4) * 8;
    const unsigned short* pb4 = W4t + (size_t)(nt * 16 + (lane & 15)) * 512 + (lane >> 4) * 8;
    f32x4 acc3 = (f32x4)(0.f), acc4 = (f32x4)(0.f);
#pragma unroll
    for (int t = 0; t < 16; ++t) {
        bf16x8 a = *(const bf16x8*)(pa + t * 32);
        bf16x8 b3f = *(const bf16x8*)(pb3 + t * 32);
        bf16x8 b4f = *(const bf16x8*)(pb4 + t * 32);
        acc3 = __builtin_amdgcn_mfma_f32_16x16x32_bf16(a, b3f, acc3, 0, 0, 0);
        acc4 = __builtin_amdgcn_mfma_f32_16x16x32_bf16(a, b4f, acc4, 0, 0, 0);
    }
    int col = lane & 15, quad = lane >> 4;
    int j = nt * 16 + col;
    float bb3 = b3[j], bb4 = b4[j], sb = skb[j];
#pragma unroll
    for (int reg = 0; reg < 4; ++reg) {
        int row = mt * 16 + quad * 4 + reg;
        float g = sigmoidf(acc3[reg] + bb3);
        yv[(size_t)row * UU + j] = skippre[(size_t)row * UU + j] + sb + g * (acc4[reg] + bb4);
    }
}

// ---------------------------------------------------------------------------
// K9: layernorm + softmax -> attn
// ---------------------------------------------------------------------------
__device__ __forceinline__ float block_sum(float v, float* red) {
    int tid = threadIdx.x;
#pragma unroll
    for (int off = 32; off > 0; off >>= 1) v += __shfl_down(v, off);
    __syncthreads();
    if ((tid & 63) == 0) red[tid >> 6] = v;
    __syncthreads();
    float r = red[0];
#pragma unroll
    for (int i = 1; i < 8; ++i) r += red[i];
    return r;
}
__device__ __forceinline__ float block_max(float v, float* red) {
    int tid = threadIdx.x;
#pragma unroll
    for (int off = 32; off > 0; off >>= 1) v = fmaxf(v, __shfl_down(v, off));
    __syncthreads();
    if ((tid & 63) == 0) red[tid >> 6] = v;
    __syncthreads();
    float r = red[0];
#pragma unroll
    for (int i = 1; i < 8; ++i) r = fmaxf(r, red[i]);
    return r;
}

__global__ void k_lnsm(const float* __restrict__ yv, const float* __restrict__ gamma,
                       const float* __restrict__ beta, float* __restrict__ attn) {
    int b = blockIdx.x, u = threadIdx.x;
    __shared__ float red[8];
    float v = yv[(size_t)b * UU + u];
    float mu = block_sum(v, red) * (1.0f / UU);
    float d = v - mu;
    float var = block_sum(d * d, red) * (1.0f / UU);
    float z = d * rsqrtf(var + 1e-3f) * gamma[u] + beta[u];
    float m = block_max(z, red);
    float e = expf(z - m);
    float Z = block_sum(e, red);
    attn[(size_t)b * UU + u] = e / Z;
}

// ---------------------------------------------------------------------------
// K10: attn-weighted KAN-feature reduction, lane-parallel over s.
// One wave per (b, f): each lane owns 8 consecutive timesteps (bf16x8 load of
// the pre-transposed weighted input wT[b][f][:]), evaluates the closed-form
// cubic B-spline basis + silu, weights by attn[b][s], butterfly-reduces the
// 9 accumulators across the wave, and writes Aredb directly.
// grid (64 b, 32 fg) x 256 (4 waves/block, one f per wave).
// ---------------------------------------------------------------------------
__global__ __launch_bounds__(256) void k_kan_red(const unsigned short* __restrict__ wT,
                                                 const float* __restrict__ attn,
                                                 unsigned short* __restrict__ Aredb) {
    int b = blockIdx.x;
    int lane = threadIdx.x & 63;
    int f = blockIdx.y * 4 + (threadIdx.x >> 6);

    const u16x8 wv = *(const u16x8*)(wT + ((size_t)b * FF + f) * SS + lane * 8);
    const float* ap = attn + (size_t)b * UU + lane * 8;
    float4 a0 = *(const float4*)ap;
    float4 a1 = *(const float4*)(ap + 4);

    float acc[9] = {};
#pragma unroll
    for (int s = 0; s < 8; ++s) {
        float w = __uint_as_float((unsigned int)wv[s] << 16);
        float a = (s < 4) ? ((s == 0) ? a0.x : (s == 1) ? a0.y : (s == 2) ? a0.z : a0.w)
                          : ((s == 4) ? a1.x : (s == 5) ? a1.y : (s == 6) ? a1.z : a1.w);
        float t = (w + 2.2f) * 2.5f;
        float cf = floorf(fminf(fmaxf(t, -2.f), 13.f));
        int c = (int)cf;
        float u = t - cf;
        float u2 = u * u, u3 = u2 * u;
        float p0 = u3 * (1.f / 6.f);
        float p1 = (-3.f * u3 + 3.f * u2 + 3.f * u + 1.f) * (1.f / 6.f);
        float p2 = (3.f * u3 - 6.f * u2 + 4.f) * (1.f / 6.f);
        float onemu = 1.f - u;
        float p3 = onemu * onemu * onemu * (1.f / 6.f);
#pragma unroll
        for (int k2 = 0; k2 < 8; ++k2) {
            int d = c - k2;
            float v = (d == 0) ? p0 : (d == 1) ? p1 : (d == 2) ? p2 : (d == 3) ? p3 : 0.f;
            acc[k2] += a * v;
        }
        acc[8] += a * (w * sigmoidf(w));
    }

    // wave butterfly reduce all 9 accumulators
#pragma unroll
    for (int off = 1; off < 64; off <<= 1) {
#pragma unroll
        for (int k = 0; k < 9; ++k) acc[k] += __shfl_xor(acc[k], off);
    }

    if (lane == 0) {
        const float sc = 1.0f / SS;
        u16x8 ov;
#pragma unroll
        for (int k = 0; k < 8; ++k) ov[k] = f2bf(acc[k] * sc);
        *(u16x8*)(Aredb + (size_t)b * KK + f * 8) = ov;
        Aredb[(size_t)b * KK + 1024 + f] = f2bf(acc[8] * sc);
    }
}

// ---------------------------------------------------------------------------
// K12: direct current = Aredb @ Wt^T -> bf16 into comb_b left half
// ---------------------------------------------------------------------------
__global__ __launch_bounds__(64) void k_cur_direct(const unsigned short* __restrict__ Aredb,
                                                   const unsigned short* __restrict__ Wt,
                                                   unsigned short* __restrict__ comb_b) {
    int lane = threadIdx.x;
    int mt = blockIdx.x, nt = blockIdx.y;
    const unsigned short* pa = Aredb + (size_t)(mt * 16 + (lane & 15)) * KK + (lane >> 4) * 8;
    const unsigned short* pb = Wt + (size_t)(nt * 16 + (lane & 15)) * KK + (lane >> 4) * 8;
    f32x4 acc0 = (f32x4)(0.f), acc1 = (f32x4)(0.f);
#pragma unroll 6
    for (int t = 0; t < KK / 32; t += 2) {
        bf16x8 a0 = *(const bf16x8*)(pa + t * 32);
        bf16x8 b0 = *(const bf16x8*)(pb + t * 32);
        bf16x8 a1 = *(const bf16x8*)(pa + t * 32 + 32);
        bf16x8 b1v = *(const bf16x8*)(pb + t * 32 + 32);
        acc0 = __builtin_amdgcn_mfma_f32_16x16x32_bf16(a0, b0, acc0, 0, 0, 0);
        acc1 = __builtin_amdgcn_mfma_f32_16x16x32_bf16(a1, b1v, acc1, 0, 0, 0);
    }
    int col = lane & 15, quad = lane >> 4;
    int j = nt * 16 + col;
#pragma unroll
    for (int reg = 0; reg < 4; ++reg) {
        int row = mt * 16 + quad * 4 + reg;
        comb_b[(size_t)row * 1024 + j] = f2bf(acc0[reg] + acc1[reg]);
    }
}

// ---------------------------------------------------------------------------
// K13: direct gates = comb_b @ Wgt^T
// ---------------------------------------------------------------------------
__global__ __launch_bounds__(64) void k_gates_direct(const unsigned short* __restrict__ comb_b,
                                                     const unsigned short* __restrict__ Wgt,
                                                     float* __restrict__ gates) {
    int lane = threadIdx.x;
    int mt = blockIdx.x, nt = blockIdx.y;
    const unsigned short* pa = comb_b + (size_t)(mt * 16 + (lane & 15)) * 1024 + (lane >> 4) * 8;
    const unsigned short* pb = Wgt + (size_t)(nt * 16 + (lane & 15)) * 1024 + (lane >> 4) * 8;
    f32x4 acc0 = (f32x4)(0.f), acc1 = (f32x4)(0.f);
#pragma unroll 8
    for (int t = 0; t < 32; t += 2) {
        bf16x8 a0 = *(const bf16x8*)(pa + t * 32);
        bf16x8 b0 = *(const bf16x8*)(pb + t * 32);
        bf16x8 a1 = *(const bf16x8*)(pa + t * 32 + 32);
        bf16x8 b1v = *(const bf16x8*)(pb + t * 32 + 32);
        acc0 = __builtin_amdgcn_mfma_f32_16x16x32_bf16(a0, b0, acc0, 0, 0, 0);
        acc1 = __builtin_amdgcn_mfma_f32_16x16x32_bf16(a1, b1v, acc1, 0, 0, 0);
    }
    int col = lane & 15, quad = lane >> 4;
    int j = nt * 16 + col;
#pragma unroll
    for (int reg = 0; reg < 4; ++reg) {
        int row = mt * 16 + quad * 4 + reg;
        gates[(size_t)row * 2048 + j] = acc0[reg] + acc1[reg];
    }
}

// ---------------------------------------------------------------------------
// K14: elementwise cell update
// ---------------------------------------------------------------------------
__global__ void k_cell(const float* __restrict__ gates,
                       const float* __restrict__ bf_, const float* __restrict__ bi_,
                       const float* __restrict__ bc_, const float* __restrict__ bo_,
                       const float* __restrict__ c_prev, float* __restrict__ out) {
    int idx = blockIdx.x * 256 + threadIdx.x;
    if (idx >= BB * UU) return;
    int b = idx >> 9, u = idx & 511;
    const float* g = gates + (size_t)b * 2048;
    float f = sigmoidf(g[u] + bf_[u]);
    float ii = sigmoidf(g[512 + u] + bi_[u]);
    float cd = tanhf(g[1024 + u] + bc_[u]);
    float o = sigmoidf(g[1536 + u] + bo_[u]);
    float cn = f * c_prev[idx] + ii * cd;
    out[idx] = o * tanhf(cn);
    out[(size_t)BB * UU + idx] = cn;
}

// ---------------------------------------------------------------------------
extern "C" void kernel_launch(void* const* d_in, const int* in_sizes, int n_in,
                              void* d_out, int out_size, void* d_ws, size_t ws_size,
                              hipStream_t stream) {
    const float* inp   = (const float*)d_in[0];
    const float* hprev = (const float*)d_in[1];
    const float* cprev = (const float*)d_in[2];
    const float* tk    = (const float*)d_in[3];
    const float* basew = (const float*)d_in[4];
    const float* splw  = (const float*)d_in[5];
    const float* gw1   = (const float*)d_in[6];
    const float* gb1   = (const float*)d_in[7];
    const float* gw2   = (const float*)d_in[8];
    const float* gb2   = (const float*)d_in[9];
    const float* gw3   = (const float*)d_in[10];
    const float* gb3   = (const float*)d_in[11];
    const float* gw4   = (const float*)d_in[12];
    const float* gb4   = (const float*)d_in[13];
    const float* gsw   = (const float*)d_in[14];
    const float* gsb   = (const float*)d_in[15];
    const float* lng   = (const float*)d_in[16];
    const float* lnb   = (const float*)d_in[17];
    const float* wf    = (const float*)d_in[18];
    const float* bf_   = (const float*)d_in[19];
    const float* wi    = (const float*)d_in[20];
    const float* bi_   = (const float*)d_in[21];
    const float* wc    = (const float*)d_in[22];
    const float* bc_   = (const float*)d_in[23];
    const float* wo    = (const float*)d_in[24];
    const float* bo_   = (const float*)d_in[25];
    float* out = (float*)d_out;

    float* ws = (float*)d_ws;
    size_t o = 0;
    unsigned short* W1t = (unsigned short*)(ws + o); o += (size_t)UU * K3 / 2;   // 16.9 MB
    unsigned short* Wst = (unsigned short*)(ws + o); o += (size_t)UU * K3 / 2;   // 16.9 MB
    unsigned short* Wt  = (unsigned short*)(ws + o); o += (size_t)UU * KK / 2;
    float* s2part   = ws + o; o += (size_t)4 * BB * FF * FF;                     // 16.78 MB
    unsigned short* aT = (unsigned short*)(ws + o); o += (size_t)BB * FF * SS / 2;  // 8.4 MB
    unsigned short* dT = (unsigned short*)(ws + o); o += (size_t)BB * FF * SS / 2;  // 8.4 MB
    unsigned short* wT = (unsigned short*)(ws + o); o += (size_t)BB * FF * SS / 2;  // 8.4 MB
    unsigned short* sigb = (unsigned short*)(ws + o); o += (size_t)BB * K3 / 2;
    float* skippre  = ws + o; o += (size_t)BB * UU;
    unsigned short* h1b = (unsigned short*)(ws + o); o += (size_t)BB * UU / 2;
    unsigned short* h2b = (unsigned short*)(ws + o); o += (size_t)BB * UU / 2;
    float* yv       = ws + o; o += (size_t)BB * UU;
    float* attn     = ws + o; o += (size_t)BB * UU;
    unsigned short* Aredb = (unsigned short*)(ws + o); o += (size_t)BB * KK / 2;
    unsigned short* W2t = (unsigned short*)(ws + o); o += (size_t)512 * 512 / 2;
    unsigned short* W3t = (unsigned short*)(ws + o); o += (size_t)512 * 512 / 2;
    unsigned short* W4t = (unsigned short*)(ws + o); o += (size_t)512 * 512 / 2;
    unsigned short* Wgt = (unsigned short*)(ws + o); o += (size_t)2048 * 1024 / 2;
    unsigned short* comb_b = (unsigned short*)(ws + o); o += (size_t)BB * 1024 / 2;
    float* gates    = ws + o; o += (size_t)BB * 2048;
    (void)ws_size; (void)in_sizes; (void)n_in; (void)out_size;

    k_wprep<<<(UU * KK + 255) / 256, 256, 0, stream>>>(splw, basew, hprev, Wt, comb_b);
    k_wt3<<<dim3(16, 8, 7), 256, 0, stream>>>(gw2, gw3, gw4, wf, wi, wc, wo, W2t, W3t, W4t, Wgt);
    k_wt2<<<dim3(K3 / 64, UU / 64, 2), 256, 0, stream>>>(gw1, gsw, W1t, Wst);
    k_adprep<<<dim3(8, 2, BB), 256, 0, stream>>>(inp, tk, aT, dT, wT);
    k_sig_mfma<<<dim3(4, BB), 256, 0, stream>>>(aT, dT, s2part);
    k_sig_reduce<<<(BB * SIGDIM + 255) / 256, 256, 0, stream>>>(inp, tk, s2part, sigb);
    k_sig_direct<<<dim3(4, 32, 2), 64, 0, stream>>>(sigb, W1t, Wst, gb1, h1b, skippre);
    k_h2_direct<<<dim3(4, 32), 64, 0, stream>>>(h1b, W2t, gb2, h2b);
    k_glu_direct<<<dim3(4, 32), 64, 0, stream>>>(h2b, W3t, W4t, gb3, gb4, skippre, gsb, yv);
    k_lnsm<<<BB, UU, 0, stream>>>(yv, lng, lnb, attn);
    k_kan_red<<<dim3(BB, FF / 4), 256, 0, stream>>>(wT, attn, Aredb);
    k_cur_direct<<<dim3(4, 32), 64, 0, stream>>>(Aredb, Wt, comb_b);
    k_gates_direct<<<dim3(4, 128), 64, 0, stream>>>(comb_b, Wgt, gates);
    k_cell<<<(BB * UU + 255) / 256, 256, 0, stream>>>(gates, bf_, bi_, bc_, bo_, cprev, out);
}

// Round 3
// 252.051 us; speedup vs baseline: 1.1991x; 1.0865x over previous
//
#include <hip/hip_runtime.h>
#include <math.h>

#define BB 64
#define SS 512
#define FF 128
#define UU 512
#define NBB 8
#define SIGDIM (FF + FF*FF)   // 16512
#define K3 16512              // sig GEMM K
#define KK 1152               // KAN GEMM K: 1024 spline + 128 base
#define SIG_KC 43             // K-chunks for fused sig GEMM (43*6*64 = 16512)
#define SIG_STEPS 6

typedef __attribute__((ext_vector_type(8))) __bf16 bf16x8;
typedef __attribute__((ext_vector_type(8))) unsigned short u16x8;
typedef __attribute__((ext_vector_type(4))) float f32x4;

__device__ __forceinline__ unsigned short f2bf(float x) {
    unsigned int u = __float_as_uint(x);
    unsigned int r = u + 0x7FFFu + ((u >> 16) & 1u);   // RNE
    return (unsigned short)(r >> 16);
}

__device__ __forceinline__ float sigmoidf(float x) { return 1.0f / (1.0f + expf(-x)); }

// ---------------------------------------------------------------------------
// K1: Wt bf16 [512 u][1152 k] = [splw(u,:,:) flat | base_w^T]
//     + copy h_prev into right half of comb_b
// ---------------------------------------------------------------------------
__global__ void k_wprep(const float* __restrict__ splw, const float* __restrict__ basew,
                        const float* __restrict__ h_prev,
                        unsigned short* __restrict__ Wt, unsigned short* __restrict__ comb_b) {
    int idx = blockIdx.x * 256 + threadIdx.x;
    if (idx >= UU * KK) return;
    int u = idx / KK, c = idx % KK;
    float v = (c < 1024) ? splw[(size_t)u * 1024 + c] : basew[(size_t)(c - 1024) * UU + u];
    Wt[idx] = f2bf(v);
    if (idx < BB * UU) {
        int b = idx >> 9, uu = idx & 511;
        comb_b[(size_t)b * 1024 + 512 + uu] = f2bf(h_prev[idx]);
    }
}

// ---------------------------------------------------------------------------
// K2: transpose small weights -> bf16 B^T.  float4 loads into fp32 LDS tile,
// packed u16x8 transposed stores (16 B/lane).
// ---------------------------------------------------------------------------
__global__ __launch_bounds__(256) void k_wt3(const float* __restrict__ w2, const float* __restrict__ w3,
                                             const float* __restrict__ w4, const float* __restrict__ wf,
                                             const float* __restrict__ wi, const float* __restrict__ wc,
                                             const float* __restrict__ wo,
                                             unsigned short* __restrict__ W2t,
                                             unsigned short* __restrict__ W3t,
                                             unsigned short* __restrict__ W4t,
                                             unsigned short* __restrict__ Wgt) {
    int kt = blockIdx.x, ut = blockIdx.y, z = blockIdx.z;
    int Kdim = (z < 3) ? 512 : 1024;
    if (kt * 64 >= Kdim) return;
    const float* src;
    unsigned short* dst;
    switch (z) {
        case 0: src = w2; dst = W2t; break;
        case 1: src = w3; dst = W3t; break;
        case 2: src = w4; dst = W4t; break;
        case 3: src = wf; dst = Wgt; break;
        case 4: src = wi; dst = Wgt + (size_t)512 * 1024; break;
        case 5: src = wc; dst = Wgt + (size_t)1024 * 1024; break;
        default: src = wo; dst = Wgt + (size_t)1536 * 1024; break;
    }
    __shared__ float tile[64][67];
    int tid = threadIdx.x;
    int k0 = kt * 64, u0 = ut * 64;
#pragma unroll
    for (int p = 0; p < 4; ++p) {
        int e = p * 256 + tid;
        int kk = e >> 4, c4 = (e & 15) * 4;
        const float4 v = *(const float4*)(src + (size_t)(k0 + kk) * UU + u0 + c4);
        tile[kk][c4 + 0] = v.x;
        tile[kk][c4 + 1] = v.y;
        tile[kk][c4 + 2] = v.z;
        tile[kk][c4 + 3] = v.w;
    }
    __syncthreads();
    int kk0 = (tid & 7) * 8;
#pragma unroll
    for (int p = 0; p < 2; ++p) {
        int uu = (tid >> 3) + p * 32;
        u16x8 ov;
#pragma unroll
        for (int j = 0; j < 8; ++j) ov[j] = f2bf(tile[kk0 + j][uu]);
        *(u16x8*)(dst + (size_t)(u0 + uu) * Kdim + k0 + kk0) = ov;
    }
}

// ---------------------------------------------------------------------------
// K4a: a/d/w prep, single fp32 LDS tile.
// ---------------------------------------------------------------------------
__global__ __launch_bounds__(256) void k_adprep(const float* __restrict__ inp,
                                                const float* __restrict__ tk,
                                                unsigned short* __restrict__ aT,
                                                unsigned short* __restrict__ dT,
                                                unsigned short* __restrict__ wT) {
    int tt0 = blockIdx.x * 64, f0 = blockIdx.y * 64, b = blockIdx.z;
    __shared__ float wS[65][67];
    __shared__ float w0S[64];
    int tid = threadIdx.x;
    const float* ib = inp + (size_t)b * SS * FF;
    if (tid < 64) w0S[tid] = tk[0] * ib[f0 + tid];
#pragma unroll
    for (int p = 0; p < 5; ++p) {
        int e = p * 256 + tid;
        if (e < 65 * 16) {
            int row = e >> 4, c4 = (e & 15) * 4;
            int t = tt0 + row;
            if (t < SS) {
                float tkt = tk[t];
                const float4 v = *(const float4*)(ib + (size_t)t * FF + f0 + c4);
                wS[row][c4 + 0] = tkt * v.x;
                wS[row][c4 + 1] = tkt * v.y;
                wS[row][c4 + 2] = tkt * v.z;
                wS[row][c4 + 3] = tkt * v.w;
            } else {
                wS[row][c4 + 0] = 0.f;
                wS[row][c4 + 1] = 0.f;
                wS[row][c4 + 2] = 0.f;
                wS[row][c4 + 3] = 0.f;
            }
        }
    }
    __syncthreads();
    int t8 = (tid & 7) * 8;
#pragma unroll
    for (int p = 0; p < 2; ++p) {
        int ff = (tid >> 3) + p * 32;
        float w0 = w0S[ff];
        u16x8 av, dv, wv;
#pragma unroll
        for (int j = 0; j < 8; ++j) {
            int tt = t8 + j;
            float w = wS[tt][ff];
            float wn = wS[tt + 1][ff];
            bool valid = (tt0 + tt) < (SS - 1);
            float a = valid ? 0.5f * (w + wn) - w0 : 0.f;
            float d = valid ? wn - w : 0.f;
            av[j] = f2bf(a);
            dv[j] = f2bf(d);
            wv[j] = f2bf(w);
        }
        size_t o = ((size_t)b * FF + f0 + ff) * SS + tt0 + t8;
        *(u16x8*)(aT + o) = av;
        *(u16x8*)(dT + o) = dv;
        *(u16x8*)(wT + o) = wv;
    }
}

// ---------------------------------------------------------------------------
// K4b: signature MFMA GEMM: s2part[kc][b] = aT[b](128x128 K-slice) . dT[b]^T
// ---------------------------------------------------------------------------
__global__ __launch_bounds__(256) void k_sig_mfma(const unsigned short* __restrict__ aT,
                                                  const unsigned short* __restrict__ dT,
                                                  float* __restrict__ s2part) {
    int kc = blockIdx.x, b = blockIdx.y;
    int tid = threadIdx.x, lane = tid & 63;
    int wv = __builtin_amdgcn_readfirstlane(tid >> 6);
    int wrow = (wv & 1) * 64, wcol = (wv >> 1) * 64;
    int k0 = kc * 128;
    const unsigned short* pa = aT + ((size_t)b * FF + wrow + (lane & 15)) * SS + k0 + (lane >> 4) * 8;
    const unsigned short* pd = dT + ((size_t)b * FF + wcol + (lane & 15)) * SS + k0 + (lane >> 4) * 8;
    f32x4 acc[4][4];
#pragma unroll
    for (int i = 0; i < 4; ++i)
#pragma unroll
        for (int j = 0; j < 4; ++j) acc[i][j] = (f32x4)(0.f);
#pragma unroll
    for (int t = 0; t < 4; ++t) {
        bf16x8 af[4], df[4];
#pragma unroll
        for (int rt = 0; rt < 4; ++rt) af[rt] = *(const bf16x8*)(pa + (size_t)rt * 16 * SS + t * 32);
#pragma unroll
        for (int ct = 0; ct < 4; ++ct) df[ct] = *(const bf16x8*)(pd + (size_t)ct * 16 * SS + t * 32);
#pragma unroll
        for (int rt = 0; rt < 4; ++rt)
#pragma unroll
            for (int ct = 0; ct < 4; ++ct)
                acc[rt][ct] = __builtin_amdgcn_mfma_f32_16x16x32_bf16(af[rt], df[ct], acc[rt][ct], 0, 0, 0);
    }
    float* outp = s2part + ((size_t)kc * BB + b) * (FF * FF);
    int quad = lane >> 4, col = lane & 15;
#pragma unroll
    for (int rt = 0; rt < 4; ++rt)
#pragma unroll
        for (int ct = 0; ct < 4; ++ct)
#pragma unroll
            for (int reg = 0; reg < 4; ++reg)
                outp[(wrow + rt * 16 + quad * 4 + reg) * FF + wcol + ct * 16 + col] = acc[rt][ct][reg];
}

// ---------------------------------------------------------------------------
// K5: assemble sig directly as bf16
// ---------------------------------------------------------------------------
__global__ void k_sig_reduce(const float* __restrict__ inp, const float* __restrict__ tk,
                             const float* __restrict__ s2part, unsigned short* __restrict__ sigb) {
    int idx = blockIdx.x * 256 + threadIdx.x;
    if (idx >= BB * SIGDIM) return;
    int b = idx / SIGDIM, r = idx % SIGDIM;
    float v;
    if (r < FF) {
        v = tk[SS - 1] * inp[((size_t)b * SS + SS - 1) * FF + r] - tk[0] * inp[(size_t)b * SS * FF + r];
    } else {
        int ij = r - FF;
        v = 0.f;
#pragma unroll
        for (int c = 0; c < 4; ++c) v += s2part[((size_t)c * BB + b) * (FF * FF) + ij];
    }
    sigb[idx] = f2bf(v);
}

// ---------------------------------------------------------------------------
// K6 (fused): {h1pre, skippre} partials = sigb[64][16512] @ {w1, gsw}
// WITHOUT pre-transposing the weights.  Per block: stage a 64k x 64u fp32
// weight tile in LDS (coalesced float4 from the original [K][U] layout),
// build transposed bf16 B-fragments on read-out, MFMA against global-direct
// A-fragments (sigb is L2-resident).  K split into 43 chunks of 6x64;
// partials (fp32) summed by k_sig_red2.
// grid (8 nt, 43 kc, 2 mat) x 256 (4 waves, 16-wide n-slice each, M=64).
// ---------------------------------------------------------------------------
__global__ __launch_bounds__(256) void k_sig_fused(const unsigned short* __restrict__ sigb,
                                                   const float* __restrict__ w1,
                                                   const float* __restrict__ gsw,
                                                   float* __restrict__ spart) {
    int nt = blockIdx.x, kc = blockIdx.y, mat = blockIdx.z;
    const float* src = mat ? gsw : w1;
    __shared__ float tile[64][67];
    int tid = threadIdx.x, lane = tid & 63;
    int wv = __builtin_amdgcn_readfirstlane(tid >> 6);
    int u0 = nt * 64;
    int n0 = wv * 16;
    int kbase = kc * (SIG_STEPS * 64);

    f32x4 acc[4];
#pragma unroll
    for (int i = 0; i < 4; ++i) acc[i] = (f32x4)(0.f);

    int nn = lane & 15;
    int kq = (lane >> 4) * 8;
    const unsigned short* pab = sigb + (size_t)nn * K3 + kq;

    for (int step = 0; step < SIG_STEPS; ++step) {
        int k0 = kbase + step * 64;
        // stage weight tile [64 k][64 u] fp32, coalesced float4
#pragma unroll
        for (int p = 0; p < 4; ++p) {
            int e = p * 256 + tid;
            int kk = e >> 4, c4 = (e & 15) * 4;
            const float4 v = *(const float4*)(src + (size_t)(k0 + kk) * UU + u0 + c4);
            tile[kk][c4 + 0] = v.x;
            tile[kk][c4 + 1] = v.y;
            tile[kk][c4 + 2] = v.z;
            tile[kk][c4 + 3] = v.w;
        }
        __syncthreads();
#pragma unroll
        for (int s = 0; s < 2; ++s) {
            // B fragment: W^T[n][k] = src[k][n], transposed read from LDS
            u16x8 ub;
            int kb = s * 32 + kq;
#pragma unroll
            for (int j = 0; j < 8; ++j) ub[j] = f2bf(tile[kb + j][n0 + nn]);
            bf16x8 bfrag = __builtin_bit_cast(bf16x8, ub);
            // A fragments: direct global (L2-resident sigb)
#pragma unroll
            for (int rt = 0; rt < 4; ++rt) {
                bf16x8 afrag = *(const bf16x8*)(pab + (size_t)(rt * 16) * K3 + k0 + s * 32);
                acc[rt] = __builtin_amdgcn_mfma_f32_16x16x32_bf16(afrag, bfrag, acc[rt], 0, 0, 0);
            }
        }
        __syncthreads();
    }

    int col = lane & 15, quad = lane >> 4;
    float* P = spart + ((size_t)(mat * SIG_KC + kc) * 64) * UU;
#pragma unroll
    for (int rt = 0; rt < 4; ++rt)
#pragma unroll
        for (int reg = 0; reg < 4; ++reg)
            P[(size_t)(rt * 16 + quad * 4 + reg) * UU + u0 + n0 + col] = acc[rt][reg];
}

// ---------------------------------------------------------------------------
// K6b: reduce 43 K-chunk partials; mat0 -> bias + ELU -> h1b (bf16),
// mat1 -> skippre (fp32).
// ---------------------------------------------------------------------------
__global__ __launch_bounds__(256) void k_sig_red2(const float* __restrict__ spart,
                                                  const float* __restrict__ b1,
                                                  unsigned short* __restrict__ h1b,
                                                  float* __restrict__ skippre) {
    int idx = blockIdx.x * 256 + threadIdx.x;   // 2 * 64 * 512 = 65536
    int mat = idx >> 15;
    int rem = idx & 32767;
    int m = rem >> 9, n = rem & 511;
    const float* p = spart + ((size_t)(mat * SIG_KC) * 64 + m) * UU + n;
    float v = 0.f;
#pragma unroll
    for (int kc = 0; kc < SIG_KC; ++kc) v += p[(size_t)kc * 64 * UU];
    if (mat == 0) {
        v += b1[n];
        h1b[(size_t)m * UU + n] = f2bf(v > 0.f ? v : expf(v) - 1.0f);
    } else {
        skippre[(size_t)m * UU + n] = v;
    }
}

// ---------------------------------------------------------------------------
// K7: direct h2 = h1b @ W2t^T + b2 -> bf16
// ---------------------------------------------------------------------------
__global__ __launch_bounds__(64) void k_h2_direct(const unsigned short* __restrict__ h1b,
                                                  const unsigned short* __restrict__ W2t,
                                                  const float* __restrict__ b2,
                                                  unsigned short* __restrict__ h2b) {
    int lane = threadIdx.x;
    int mt = blockIdx.x, nt = blockIdx.y;
    const unsigned short* pa = h1b + (size_t)(mt * 16 + (lane & 15)) * 512 + (lane >> 4) * 8;
    const unsigned short* pb = W2t + (size_t)(nt * 16 + (lane & 15)) * 512 + (lane >> 4) * 8;
    f32x4 acc0 = (f32x4)(0.f), acc1 = (f32x4)(0.f);
#pragma unroll
    for (int t = 0; t < 16; t += 2) {
        bf16x8 a0 = *(const bf16x8*)(pa + t * 32);
        bf16x8 b0 = *(const bf16x8*)(pb + t * 32);
        bf16x8 a1 = *(const bf16x8*)(pa + t * 32 + 32);
        bf16x8 b1v = *(const bf16x8*)(pb + t * 32 + 32);
        acc0 = __builtin_amdgcn_mfma_f32_16x16x32_bf16(a0, b0, acc0, 0, 0, 0);
        acc1 = __builtin_amdgcn_mfma_f32_16x16x32_bf16(a1, b1v, acc1, 0, 0, 0);
    }
    int col = lane & 15, quad = lane >> 4;
    int j = nt * 16 + col;
    float bb = b2[j];
#pragma unroll
    for (int reg = 0; reg < 4; ++reg) {
        int row = mt * 16 + quad * 4 + reg;
        h2b[(size_t)row * UU + j] = f2bf(acc0[reg] + acc1[reg] + bb);
    }
}

// ---------------------------------------------------------------------------
// K8: direct GLU
// ---------------------------------------------------------------------------
__global__ __launch_bounds__(64) void k_glu_direct(const unsigned short* __restrict__ h2b,
                                                   const unsigned short* __restrict__ W3t,
                                                   const unsigned short* __restrict__ W4t,
                                                   const float* __restrict__ b3,
                                                   const float* __restrict__ b4,
                                                   const float* __restrict__ skippre,
                                                   const float* __restrict__ skb,
                                                   float* __restrict__ yv) {
    int lane = threadIdx.x;
    int mt = blockIdx.x, nt = blockIdx.y;
    const unsigned short* pa = h2b + (size_t)(mt * 16 + (lane & 15)) * 512 + (lane >> 4) * 8;
    const unsigned short* pb3 = W3t + (size_t)(nt * 16 + (lane & 15)) * 512 + (lane >> 4) * 8;
    const unsigned short* pb4 = W4t + (size_t)(nt * 16 + (lane & 15)) * 512 + (lane >> 4) * 8;
    f32x4 acc3 = (f32x4)(0.f), acc4 = (f32x4)(0.f);
#pragma unroll
    for (int t = 0; t < 16; ++t) {
        bf16x8 a = *(const bf16x8*)(pa + t * 32);
        bf16x8 b3f = *(const bf16x8*)(pb3 + t * 32);
        bf16x8 b4f = *(const bf16x8*)(pb4 + t * 32);
        acc3 = __builtin_amdgcn_mfma_f32_16x16x32_bf16(a, b3f, acc3, 0, 0, 0);
        acc4 = __builtin_amdgcn_mfma_f32_16x16x32_bf16(a, b4f, acc4, 0, 0, 0);
    }
    int col = lane & 15, quad = lane >> 4;
    int j = nt * 16 + col;
    float bb3 = b3[j], bb4 = b4[j], sb = skb[j];
#pragma unroll
    for (int reg = 0; reg < 4; ++reg) {
        int row = mt * 16 + quad * 4 + reg;
        float g = sigmoidf(acc3[reg] + bb3);
        yv[(size_t)row * UU + j] = skippre[(size_t)row * UU + j] + sb + g * (acc4[reg] + bb4);
    }
}

// ---------------------------------------------------------------------------
// K9: layernorm + softmax -> attn
// ---------------------------------------------------------------------------
__device__ __forceinline__ float block_sum(float v, float* red) {
    int tid = threadIdx.x;
#pragma unroll
    for (int off = 32; off > 0; off >>= 1) v += __shfl_down(v, off);
    __syncthreads();
    if ((tid & 63) == 0) red[tid >> 6] = v;
    __syncthreads();
    float r = red[0];
#pragma unroll
    for (int i = 1; i < 8; ++i) r += red[i];
    return r;
}
__device__ __forceinline__ float block_max(float v, float* red) {
    int tid = threadIdx.x;
#pragma unroll
    for (int off = 32; off > 0; off >>= 1) v = fmaxf(v, __shfl_down(v, off));
    __syncthreads();
    if ((tid & 63) == 0) red[tid >> 6] = v;
    __syncthreads();
    float r = red[0];
#pragma unroll
    for (int i = 1; i < 8; ++i) r = fmaxf(r, red[i]);
    return r;
}

__global__ void k_lnsm(const float* __restrict__ yv, const float* __restrict__ gamma,
                       const float* __restrict__ beta, float* __restrict__ attn) {
    int b = blockIdx.x, u = threadIdx.x;
    __shared__ float red[8];
    float v = yv[(size_t)b * UU + u];
    float mu = block_sum(v, red) * (1.0f / UU);
    float d = v - mu;
    float var = block_sum(d * d, red) * (1.0f / UU);
    float z = d * rsqrtf(var + 1e-3f) * gamma[u] + beta[u];
    float m = block_max(z, red);
    float e = expf(z - m);
    float Z = block_sum(e, red);
    attn[(size_t)b * UU + u] = e / Z;
}

// ---------------------------------------------------------------------------
// K10: attn-weighted KAN-feature reduction, lane-parallel over s.
// ---------------------------------------------------------------------------
__global__ __launch_bounds__(256) void k_kan_red(const unsigned short* __restrict__ wT,
                                                 const float* __restrict__ attn,
                                                 unsigned short* __restrict__ Aredb) {
    int b = blockIdx.x;
    int lane = threadIdx.x & 63;
    int f = blockIdx.y * 4 + (threadIdx.x >> 6);

    const u16x8 wv = *(const u16x8*)(wT + ((size_t)b * FF + f) * SS + lane * 8);
    const float* ap = attn + (size_t)b * UU + lane * 8;
    float4 a0 = *(const float4*)ap;
    float4 a1 = *(const float4*)(ap + 4);

    float acc[9] = {};
#pragma unroll
    for (int s = 0; s < 8; ++s) {
        float w = __uint_as_float((unsigned int)wv[s] << 16);
        float a = (s < 4) ? ((s == 0) ? a0.x : (s == 1) ? a0.y : (s == 2) ? a0.z : a0.w)
                          : ((s == 4) ? a1.x : (s == 5) ? a1.y : (s == 6) ? a1.z : a1.w);
        float t = (w + 2.2f) * 2.5f;
        float cf = floorf(fminf(fmaxf(t, -2.f), 13.f));
        int c = (int)cf;
        float u = t - cf;
        float u2 = u * u, u3 = u2 * u;
        float p0 = u3 * (1.f / 6.f);
        float p1 = (-3.f * u3 + 3.f * u2 + 3.f * u + 1.f) * (1.f / 6.f);
        float p2 = (3.f * u3 - 6.f * u2 + 4.f) * (1.f / 6.f);
        float onemu = 1.f - u;
        float p3 = onemu * onemu * onemu * (1.f / 6.f);
#pragma unroll
        for (int k2 = 0; k2 < 8; ++k2) {
            int d = c - k2;
            float v = (d == 0) ? p0 : (d == 1) ? p1 : (d == 2) ? p2 : (d == 3) ? p3 : 0.f;
            acc[k2] += a * v;
        }
        acc[8] += a * (w * sigmoidf(w));
    }

#pragma unroll
    for (int off = 1; off < 64; off <<= 1) {
#pragma unroll
        for (int k = 0; k < 9; ++k) acc[k] += __shfl_xor(acc[k], off);
    }

    if (lane == 0) {
        const float sc = 1.0f / SS;
        u16x8 ov;
#pragma unroll
        for (int k = 0; k < 8; ++k) ov[k] = f2bf(acc[k] * sc);
        *(u16x8*)(Aredb + (size_t)b * KK + f * 8) = ov;
        Aredb[(size_t)b * KK + 1024 + f] = f2bf(acc[8] * sc);
    }
}

// ---------------------------------------------------------------------------
// K12: direct current = Aredb @ Wt^T -> bf16 into comb_b left half
// ---------------------------------------------------------------------------
__global__ __launch_bounds__(64) void k_cur_direct(const unsigned short* __restrict__ Aredb,
                                                   const unsigned short* __restrict__ Wt,
                                                   unsigned short* __restrict__ comb_b) {
    int lane = threadIdx.x;
    int mt = blockIdx.x, nt = blockIdx.y;
    const unsigned short* pa = Aredb + (size_t)(mt * 16 + (lane & 15)) * KK + (lane >> 4) * 8;
    const unsigned short* pb = Wt + (size_t)(nt * 16 + (lane & 15)) * KK + (lane >> 4) * 8;
    f32x4 acc0 = (f32x4)(0.f), acc1 = (f32x4)(0.f);
#pragma unroll 6
    for (int t = 0; t < KK / 32; t += 2) {
        bf16x8 a0 = *(const bf16x8*)(pa + t * 32);
        bf16x8 b0 = *(const bf16x8*)(pb + t * 32);
        bf16x8 a1 = *(const bf16x8*)(pa + t * 32 + 32);
        bf16x8 b1v = *(const bf16x8*)(pb + t * 32 + 32);
        acc0 = __builtin_amdgcn_mfma_f32_16x16x32_bf16(a0, b0, acc0, 0, 0, 0);
        acc1 = __builtin_amdgcn_mfma_f32_16x16x32_bf16(a1, b1v, acc1, 0, 0, 0);
    }
    int col = lane & 15, quad = lane >> 4;
    int j = nt * 16 + col;
#pragma unroll
    for (int reg = 0; reg < 4; ++reg) {
        int row = mt * 16 + quad * 4 + reg;
        comb_b[(size_t)row * 1024 + j] = f2bf(acc0[reg] + acc1[reg]);
    }
}

// ---------------------------------------------------------------------------
// K13: direct gates = comb_b @ Wgt^T
// ---------------------------------------------------------------------------
__global__ __launch_bounds__(64) void k_gates_direct(const unsigned short* __restrict__ comb_b,
                                                     const unsigned short* __restrict__ Wgt,
                                                     float* __restrict__ gates) {
    int lane = threadIdx.x;
    int mt = blockIdx.x, nt = blockIdx.y;
    const unsigned short* pa = comb_b + (size_t)(mt * 16 + (lane & 15)) * 1024 + (lane >> 4) * 8;
    const unsigned short* pb = Wgt + (size_t)(nt * 16 + (lane & 15)) * 1024 + (lane >> 4) * 8;
    f32x4 acc0 = (f32x4)(0.f), acc1 = (f32x4)(0.f);
#pragma unroll 8
    for (int t = 0; t < 32; t += 2) {
        bf16x8 a0 = *(const bf16x8*)(pa + t * 32);
        bf16x8 b0 = *(const bf16x8*)(pb + t * 32);
        bf16x8 a1 = *(const bf16x8*)(pa + t * 32 + 32);
        bf16x8 b1v = *(const bf16x8*)(pb + t * 32 + 32);
        acc0 = __builtin_amdgcn_mfma_f32_16x16x32_bf16(a0, b0, acc0, 0, 0, 0);
        acc1 = __builtin_amdgcn_mfma_f32_16x16x32_bf16(a1, b1v, acc1, 0, 0, 0);
    }
    int col = lane & 15, quad = lane >> 4;
    int j = nt * 16 + col;
#pragma unroll
    for (int reg = 0; reg < 4; ++reg) {
        int row = mt * 16 + quad * 4 + reg;
        gates[(size_t)row * 2048 + j] = acc0[reg] + acc1[reg];
    }
}

// ---------------------------------------------------------------------------
// K14: elementwise cell update
// ---------------------------------------------------------------------------
__global__ void k_cell(const float* __restrict__ gates,
                       const float* __restrict__ bf_, const float* __restrict__ bi_,
                       const float* __restrict__ bc_, const float* __restrict__ bo_,
                       const float* __restrict__ c_prev, float* __restrict__ out) {
    int idx = blockIdx.x * 256 + threadIdx.x;
    if (idx >= BB * UU) return;
    int b = idx >> 9, u = idx & 511;
    const float* g = gates + (size_t)b * 2048;
    float f = sigmoidf(g[u] + bf_[u]);
    float ii = sigmoidf(g[512 + u] + bi_[u]);
    float cd = tanhf(g[1024 + u] + bc_[u]);
    float o = sigmoidf(g[1536 + u] + bo_[u]);
    float cn = f * c_prev[idx] + ii * cd;
    out[idx] = o * tanhf(cn);
    out[(size_t)BB * UU + idx] = cn;
}

// ---------------------------------------------------------------------------
extern "C" void kernel_launch(void* const* d_in, const int* in_sizes, int n_in,
                              void* d_out, int out_size, void* d_ws, size_t ws_size,
                              hipStream_t stream) {
    const float* inp   = (const float*)d_in[0];
    const float* hprev = (const float*)d_in[1];
    const float* cprev = (const float*)d_in[2];
    const float* tk    = (const float*)d_in[3];
    const float* basew = (const float*)d_in[4];
    const float* splw  = (const float*)d_in[5];
    const float* gw1   = (const float*)d_in[6];
    const float* gb1   = (const float*)d_in[7];
    const float* gw2   = (const float*)d_in[8];
    const float* gb2   = (const float*)d_in[9];
    const float* gw3   = (const float*)d_in[10];
    const float* gb3   = (const float*)d_in[11];
    const float* gw4   = (const float*)d_in[12];
    const float* gb4   = (const float*)d_in[13];
    const float* gsw   = (const float*)d_in[14];
    const float* gsb   = (const float*)d_in[15];
    const float* lng   = (const float*)d_in[16];
    const float* lnb   = (const float*)d_in[17];
    const float* wf    = (const float*)d_in[18];
    const float* bf_   = (const float*)d_in[19];
    const float* wi    = (const float*)d_in[20];
    const float* bi_   = (const float*)d_in[21];
    const float* wc    = (const float*)d_in[22];
    const float* bc_   = (const float*)d_in[23];
    const float* wo    = (const float*)d_in[24];
    const float* bo_   = (const float*)d_in[25];
    float* out = (float*)d_out;

    float* ws = (float*)d_ws;
    size_t o = 0;
    unsigned short* Wt  = (unsigned short*)(ws + o); o += (size_t)UU * KK / 2;
    float* s2part   = ws + o; o += (size_t)4 * BB * FF * FF;                     // 16.78 MB
    unsigned short* aT = (unsigned short*)(ws + o); o += (size_t)BB * FF * SS / 2;  // 8.4 MB
    unsigned short* dT = (unsigned short*)(ws + o); o += (size_t)BB * FF * SS / 2;  // 8.4 MB
    unsigned short* wT = (unsigned short*)(ws + o); o += (size_t)BB * FF * SS / 2;  // 8.4 MB
    unsigned short* sigb = (unsigned short*)(ws + o); o += (size_t)BB * K3 / 2;
    float* spart    = ws + o; o += (size_t)2 * SIG_KC * 64 * UU;                 // 11.27 MB
    float* skippre  = ws + o; o += (size_t)BB * UU;
    unsigned short* h1b = (unsigned short*)(ws + o); o += (size_t)BB * UU / 2;
    unsigned short* h2b = (unsigned short*)(ws + o); o += (size_t)BB * UU / 2;
    float* yv       = ws + o; o += (size_t)BB * UU;
    float* attn     = ws + o; o += (size_t)BB * UU;
    unsigned short* Aredb = (unsigned short*)(ws + o); o += (size_t)BB * KK / 2;
    unsigned short* W2t = (unsigned short*)(ws + o); o += (size_t)512 * 512 / 2;
    unsigned short* W3t = (unsigned short*)(ws + o); o += (size_t)512 * 512 / 2;
    unsigned short* W4t = (unsigned short*)(ws + o); o += (size_t)512 * 512 / 2;
    unsigned short* Wgt = (unsigned short*)(ws + o); o += (size_t)2048 * 1024 / 2;
    unsigned short* comb_b = (unsigned short*)(ws + o); o += (size_t)BB * 1024 / 2;
    float* gates    = ws + o; o += (size_t)BB * 2048;
    (void)ws_size; (void)in_sizes; (void)n_in; (void)out_size;

    k_wprep<<<(UU * KK + 255) / 256, 256, 0, stream>>>(splw, basew, hprev, Wt, comb_b);
    k_wt3<<<dim3(16, 8, 7), 256, 0, stream>>>(gw2, gw3, gw4, wf, wi, wc, wo, W2t, W3t, W4t, Wgt);
    k_adprep<<<dim3(8, 2, BB), 256, 0, stream>>>(inp, tk, aT, dT, wT);
    k_sig_mfma<<<dim3(4, BB), 256, 0, stream>>>(aT, dT, s2part);
    k_sig_reduce<<<(BB * SIGDIM + 255) / 256, 256, 0, stream>>>(inp, tk, s2part, sigb);
    k_sig_fused<<<dim3(8, SIG_KC, 2), 256, 0, stream>>>(sigb, gw1, gsw, spart);
    k_sig_red2<<<256, 256, 0, stream>>>(spart, gb1, h1b, skippre);
    k_h2_direct<<<dim3(4, 32), 64, 0, stream>>>(h1b, W2t, gb2, h2b);
    k_glu_direct<<<dim3(4, 32), 64, 0, stream>>>(h2b, W3t, W4t, gb3, gb4, skippre, gsb, yv);
    k_lnsm<<<BB, UU, 0, stream>>>(yv, lng, lnb, attn);
    k_kan_red<<<dim3(BB, FF / 4), 256, 0, stream>>>(wT, attn, Aredb);
    k_cur_direct<<<dim3(4, 32), 64, 0, stream>>>(Aredb, Wt, comb_b);
    k_gates_direct<<<dim3(4, 128), 64, 0, stream>>>(comb_b, Wgt, gates);
    k_cell<<<(BB * UU + 255) / 256, 256, 0, stream>>>(gates, bf_, bi_, bc_, bo_, cprev, out);
}